// Round 1
// baseline (431.490 us; speedup 1.0000x reference)
//
#include <hip/hip_runtime.h>
#include <stdint.h>
#include <math.h>

#define BB 8
#define SEQ 2048
#define CDIM 384
#define NH 6
#define HD 64
#define QKVN 1152

typedef __attribute__((ext_vector_type(8))) __bf16 bf16x8;
typedef __attribute__((ext_vector_type(4))) float f32x4;
typedef __attribute__((ext_vector_type(4))) unsigned short ushort4v;

__device__ __forceinline__ unsigned short f2bf(float f) {
  unsigned int u = __float_as_uint(f);
  u += 0x7fffu + ((u >> 16) & 1u);
  return (unsigned short)(u >> 16);
}

// fp32 -> bf16 conversion, 4 elems/thread
__global__ void k_convert(const float* __restrict__ src, unsigned short* __restrict__ dst, int n4) {
  int i = blockIdx.x * blockDim.x + threadIdx.x;
  if (i >= n4) return;
  float4 f = reinterpret_cast<const float4*>(src)[i];
  ushort4v u;
  u.x = f2bf(f.x); u.y = f2bf(f.y); u.z = f2bf(f.z); u.w = f2bf(f.w);
  reinterpret_cast<ushort4v*>(dst)[i] = u;
}

__device__ __forceinline__ void gload_lds16(const unsigned short* g, unsigned short* l) {
  __builtin_amdgcn_global_load_lds((const __attribute__((address_space(1))) void*)g,
                                   (__attribute__((address_space(3))) void*)l, 16, 0, 0);
}

// C[M,Nc] = A[M,K] * Bm[Nc,K]^T   (both row-major bf16, K contiguous; m97 structure)
// OUT_F32=0: bf16 out to Cb.  OUT_F32=1: f32 out to Cf with bias.
template<int OUT_F32>
__global__ __launch_bounds__(256, 2) void k_gemm_bt(
    const unsigned short* __restrict__ A, const unsigned short* __restrict__ Bm,
    unsigned short* __restrict__ Cb, float* __restrict__ Cf,
    const float* __restrict__ bias, int M, int Nc, int K)
{
  __shared__ unsigned short lA[128 * 32];
  __shared__ unsigned short lB[128 * 32];
  const int t = threadIdx.x;
  const int w = t >> 6, l = t & 63;
  const int wr = w >> 1, wc = w & 1;
  const int row0 = blockIdx.x * 128, col0 = blockIdx.y * 128;
  const f32x4 vzero = {0.f, 0.f, 0.f, 0.f};
  f32x4 acc[4][4];
#pragma unroll
  for (int m = 0; m < 4; ++m)
#pragma unroll
    for (int n = 0; n < 4; ++n) acc[m][n] = vzero;

  // staging: thread t covers LDS bytes [w*1024 + l*16] (+4096 for round 1) == linear
  const int srow = w * 16 + (l >> 2);
  const int scol = (l & 3) * 8;
  const int lr = l & 15, kc = (l >> 4) * 8;

  for (int k0 = 0; k0 < K; k0 += 32) {
#pragma unroll
    for (int r = 0; r < 2; ++r) {
      gload_lds16(A + (size_t)(row0 + r * 64 + srow) * K + k0 + scol,
                  &lA[(r * 64 + srow) * 32 + scol]);
      gload_lds16(Bm + (size_t)(col0 + r * 64 + srow) * K + k0 + scol,
                  &lB[(r * 64 + srow) * 32 + scol]);
    }
    __syncthreads();
    bf16x8 af[4], bfr[4];
#pragma unroll
    for (int m = 0; m < 4; ++m)
      af[m] = *(const bf16x8*)&lA[(wr * 64 + m * 16 + lr) * 32 + kc];
#pragma unroll
    for (int n = 0; n < 4; ++n)
      bfr[n] = *(const bf16x8*)&lB[(wc * 64 + n * 16 + lr) * 32 + kc];
#pragma unroll
    for (int m = 0; m < 4; ++m)
#pragma unroll
      for (int n = 0; n < 4; ++n)
        acc[m][n] = __builtin_amdgcn_mfma_f32_16x16x32_bf16(af[m], bfr[n], acc[m][n], 0, 0, 0);
    __syncthreads();
  }

  // C/D layout: col = lane&15, row = (lane>>4)*4 + reg   [measured m89/m91]
#pragma unroll
  for (int m = 0; m < 4; ++m) {
    const int row = row0 + wr * 64 + m * 16 + (l >> 4) * 4;
#pragma unroll
    for (int n = 0; n < 4; ++n) {
      const int col = col0 + wc * 64 + n * 16 + (l & 15);
      if (OUT_F32) {
        const float bv = bias[col];
#pragma unroll
        for (int j = 0; j < 4; ++j)
          Cf[(size_t)(row + j) * Nc + col] = acc[m][n][j] + bv;
      } else {
#pragma unroll
        for (int j = 0; j < 4; ++j)
          Cb[(size_t)(row + j) * Nc + col] = f2bf(acc[m][n][j]);
      }
    }
  }
}

// V slice of qkv (b,n,768 + h*64 + d) -> VT[(b*H+h), d, n]  (bf16)
__global__ void k_vtrans(const unsigned short* __restrict__ qkv, unsigned short* __restrict__ vt)
{
  __shared__ unsigned short tile[64][76];  // stride 76 elems (152B) keeps 8B align, spreads banks
  const int bh = blockIdx.x;
  const int b = bh / NH, h = bh - b * NH;
  const int n0 = blockIdx.y * 64;
  const int t = threadIdx.x;
  const int rr0 = t >> 4;
  const int c4 = (t & 15) * 4;
  const unsigned short* src = qkv + (size_t)(b * SEQ + n0) * QKVN + 2 * CDIM + h * HD;
#pragma unroll
  for (int rr = 0; rr < 4; ++rr) {
    int n = rr * 16 + rr0;
    ushort4v v = *(const ushort4v*)(src + (size_t)n * QKVN + c4);
    *(ushort4v*)&tile[n][c4] = v;
  }
  __syncthreads();
  unsigned short* dst = vt + (size_t)bh * HD * SEQ + n0;
#pragma unroll
  for (int rr = 0; rr < 4; ++rr) {
    int d = rr * 16 + rr0;
    ushort4v v;
    v.x = tile[c4 + 0][d];
    v.y = tile[c4 + 1][d];
    v.z = tile[c4 + 2][d];
    v.w = tile[c4 + 3][d];
    *(ushort4v*)(dst + (size_t)d * SEQ + c4) = v;
  }
}

// Flash attention: grid (B*H, N/64), 4 waves/block, each wave owns 16 q-rows.
// Q,K read from qkv buffer (bf16), V from VT, mask fp32 from input.
__global__ __launch_bounds__(256, 2) void k_attn(
    const unsigned short* __restrict__ qkv, const float* __restrict__ mask,
    const unsigned short* __restrict__ vt, unsigned short* __restrict__ aout)
{
  const int bh = blockIdx.x;
  const int b = bh / NH, h = bh - b * NH;
  const int w = threadIdx.x >> 6, l = threadIdx.x & 63;
  const int g = l >> 4, c = l & 15;
  const int q0 = blockIdx.y * 64 + w * 16;

  __shared__ unsigned short plds[4][16 * 40];  // per-wave P-transpose tile, 80B row stride
  unsigned short* pw = plds[w];

  const unsigned short* qb = qkv + (size_t)(b * SEQ + q0) * QKVN + h * HD;
  const unsigned short* kb = qkv + (size_t)(b * SEQ) * QKVN + CDIM + h * HD;
  const unsigned short* vb = vt + (size_t)bh * HD * SEQ;
  const float* mrow = mask + ((size_t)b * SEQ + q0) * SEQ;

  // Q fragments held in registers for the whole kernel (A-frag: row=l&15, k-chunk=(l>>4)*8)
  const bf16x8 qf0 = *(const bf16x8*)(qb + (size_t)c * QKVN + g * 8);
  const bf16x8 qf1 = *(const bf16x8*)(qb + (size_t)c * QKVN + 32 + g * 8);

  const f32x4 vzero = {0.f, 0.f, 0.f, 0.f};
  f32x4 acco[4];
  float mreg[4], lreg[4];
#pragma unroll
  for (int r = 0; r < 4; ++r) { mreg[r] = -INFINITY; lreg[r] = 0.f; }
#pragma unroll
  for (int dt = 0; dt < 4; ++dt) acco[dt] = vzero;

  for (int kt = 0; kt < SEQ; kt += 32) {
    const unsigned short* k0p = kb + (size_t)(kt + c) * QKVN;
    const unsigned short* k1p = kb + (size_t)(kt + 16 + c) * QKVN;
    bf16x8 kf0a = *(const bf16x8*)(k0p + g * 8);
    bf16x8 kf0b = *(const bf16x8*)(k0p + 32 + g * 8);
    bf16x8 kf1a = *(const bf16x8*)(k1p + g * 8);
    bf16x8 kf1b = *(const bf16x8*)(k1p + 32 + g * 8);
    f32x4 s0 = vzero, s1 = vzero;
    s0 = __builtin_amdgcn_mfma_f32_16x16x32_bf16(qf0, kf0a, s0, 0, 0, 0);
    s0 = __builtin_amdgcn_mfma_f32_16x16x32_bf16(qf1, kf0b, s0, 0, 0, 0);
    s1 = __builtin_amdgcn_mfma_f32_16x16x32_bf16(qf0, kf1a, s1, 0, 0, 0);
    s1 = __builtin_amdgcn_mfma_f32_16x16x32_bf16(qf1, kf1b, s1, 0, 0, 0);

    // scores: row q0+4g+r, col kt+c (s0) / kt+16+c (s1); mask applied in fp32
    float x0[4], x1[4], tm[4];
#pragma unroll
    for (int r = 0; r < 4; ++r) {
      float m0 = mrow[(size_t)(4 * g + r) * SEQ + kt + c];
      float m1 = mrow[(size_t)(4 * g + r) * SEQ + kt + 16 + c];
      x0[r] = fmaf(m0, -100000.0f, s0[r] * 0.125f);
      x1[r] = fmaf(m1, -100000.0f, s1[r] * 0.125f);
      tm[r] = fmaxf(x0[r], x1[r]);
    }
#pragma unroll
    for (int off = 1; off < 16; off <<= 1)
#pragma unroll
      for (int r = 0; r < 4; ++r)
        tm[r] = fmaxf(tm[r], __shfl_xor(tm[r], off));

    float p0[4], p1[4], rs[4], al[4];
#pragma unroll
    for (int r = 0; r < 4; ++r) {
      float mn = fmaxf(mreg[r], tm[r]);
      al[r] = __expf(mreg[r] - mn);
      p0[r] = __expf(x0[r] - mn);
      p1[r] = __expf(x1[r] - mn);
      rs[r] = p0[r] + p1[r];
      mreg[r] = mn;
    }
#pragma unroll
    for (int off = 1; off < 16; off <<= 1)
#pragma unroll
      for (int r = 0; r < 4; ++r)
        rs[r] += __shfl_xor(rs[r], off);
#pragma unroll
    for (int r = 0; r < 4; ++r)
      lreg[r] = lreg[r] * al[r] + rs[r];
#pragma unroll
    for (int dt = 0; dt < 4; ++dt)
#pragma unroll
      for (int r = 0; r < 4; ++r)
        acco[dt][r] *= al[r];

    // P (16x32) -> LDS (accum layout) -> A-frag layout; wave-private region,
    // compiler barriers defeat TBAA reordering of ushort stores vs bf16x8 load
    __asm__ volatile("" ::: "memory");
#pragma unroll
    for (int r = 0; r < 4; ++r) {
      pw[(4 * g + r) * 40 + c] = f2bf(p0[r]);
      pw[(4 * g + r) * 40 + 16 + c] = f2bf(p1[r]);
    }
    __asm__ volatile("" ::: "memory");
    bf16x8 pf = *(const bf16x8*)&pw[c * 40 + g * 8];
#pragma unroll
    for (int dt = 0; dt < 4; ++dt) {
      // B-frag from VT: lane holds V[k=kt+g*8+j, d=dt*16+c] = VT[dt*16+c, kt+g*8+j]
      bf16x8 vf = *(const bf16x8*)(vb + (size_t)(dt * 16 + c) * SEQ + kt + g * 8);
      acco[dt] = __builtin_amdgcn_mfma_f32_16x16x32_bf16(pf, vf, acco[dt], 0, 0, 0);
    }
  }

  // out (B,N,C) bf16: row q0+4g+r, col h*64 + dt*16 + c
  unsigned short* ob = aout + (size_t)(b * SEQ + q0) * CDIM + h * HD;
#pragma unroll
  for (int dt = 0; dt < 4; ++dt)
#pragma unroll
    for (int r = 0; r < 4; ++r) {
      float ov = acco[dt][r] / lreg[r];
      ob[(size_t)(4 * g + r) * CDIM + dt * 16 + c] = f2bf(ov);
    }
}

extern "C" void kernel_launch(void* const* d_in, const int* in_sizes, int n_in,
                              void* d_out, int out_size, void* d_ws, size_t ws_size,
                              hipStream_t stream) {
  (void)in_sizes; (void)n_in; (void)out_size; (void)ws_size;
  const float* x      = (const float*)d_in[0];
  const float* mask   = (const float*)d_in[2];
  const float* qkv_w  = (const float*)d_in[3];
  const float* proj_w = (const float*)d_in[4];
  const float* proj_b = (const float*)d_in[5];
  float* out = (float*)d_out;
  char* ws = (char*)d_ws;

  // workspace layout (bytes), total 76,677,120
  unsigned short* xb    = (unsigned short*)(ws + 0);         // x bf16:      12,582,912
  unsigned short* wqb   = (unsigned short*)(ws + 12582912);  // qkv_w bf16:     884,736
  unsigned short* wpb   = (unsigned short*)(ws + 13467648);  // proj_w bf16:    294,912
  unsigned short* qkvb  = (unsigned short*)(ws + 13762560);  // qkv bf16:    37,748,736
  unsigned short* vtb   = (unsigned short*)(ws + 51511296);  // V^T bf16:    12,582,912
  unsigned short* aoutb = (unsigned short*)(ws + 64094208);  // attn out:    12,582,912

  k_convert<<<6144, 256, 0, stream>>>(x, xb, 1572864);
  k_convert<<<432, 256, 0, stream>>>(qkv_w, wqb, 110592);
  k_convert<<<144, 256, 0, stream>>>(proj_w, wpb, 36864);
  // qkv = x @ qkv_w.T : M=16384, N=1152, K=384
  k_gemm_bt<0><<<dim3(128, 9), 256, 0, stream>>>(xb, wqb, qkvb, nullptr, nullptr, 16384, 1152, 384);
  k_vtrans<<<dim3(48, 32), 256, 0, stream>>>(qkvb, vtb);
  k_attn<<<dim3(48, 32), 256, 0, stream>>>(qkvb, mask, vtb, aoutb);
  // out = attn_out @ proj_w.T + proj_b : M=16384, N=384, K=384
  k_gemm_bt<1><<<dim3(128, 3), 256, 0, stream>>>(aoutb, wpb, nullptr, out, proj_b, 16384, 384, 384);
}

// Round 2
// 232.695 us; speedup vs baseline: 1.8543x; 1.8543x over previous
//
#include <hip/hip_runtime.h>
#include <stdint.h>
#include <math.h>

#define BB 8
#define SEQ 2048
#define CDIM 384
#define NH 6
#define HD 64
#define QKVN 1152

typedef __attribute__((ext_vector_type(8))) __bf16 bf16x8;
typedef __attribute__((ext_vector_type(4))) float f32x4;
typedef __attribute__((ext_vector_type(4))) unsigned short ushort4v;

__device__ __forceinline__ unsigned short f2bf(float f) {
  unsigned int u = __float_as_uint(f);
  u += 0x7fffu + ((u >> 16) & 1u);
  return (unsigned short)(u >> 16);
}

// fp32 -> bf16 conversion, 4 elems/thread
__global__ void k_convert(const float* __restrict__ src, unsigned short* __restrict__ dst, int n4) {
  int i = blockIdx.x * blockDim.x + threadIdx.x;
  if (i >= n4) return;
  float4 f = reinterpret_cast<const float4*>(src)[i];
  ushort4v u;
  u.x = f2bf(f.x); u.y = f2bf(f.y); u.z = f2bf(f.z); u.w = f2bf(f.w);
  reinterpret_cast<ushort4v*>(dst)[i] = u;
}

__device__ __forceinline__ void gload_lds16(const unsigned short* g, unsigned short* l) {
  __builtin_amdgcn_global_load_lds((const __attribute__((address_space(1))) void*)g,
                                   (__attribute__((address_space(3))) void*)l, 16, 0, 0);
}

// C[M,Nc] = A[M,K] * Bm[Nc,K]^T   (both row-major bf16, K contiguous; m97 structure)
template<int OUT_F32>
__global__ __launch_bounds__(256, 2) void k_gemm_bt(
    const unsigned short* __restrict__ A, const unsigned short* __restrict__ Bm,
    unsigned short* __restrict__ Cb, float* __restrict__ Cf,
    const float* __restrict__ bias, int M, int Nc, int K)
{
  __shared__ unsigned short lA[128 * 32];
  __shared__ unsigned short lB[128 * 32];
  const int t = threadIdx.x;
  const int w = t >> 6, l = t & 63;
  const int wr = w >> 1, wc = w & 1;
  const int row0 = blockIdx.x * 128, col0 = blockIdx.y * 128;
  const f32x4 vzero = {0.f, 0.f, 0.f, 0.f};
  f32x4 acc[4][4];
#pragma unroll
  for (int m = 0; m < 4; ++m)
#pragma unroll
    for (int n = 0; n < 4; ++n) acc[m][n] = vzero;

  const int srow = w * 16 + (l >> 2);
  const int scol = (l & 3) * 8;
  const int lr = l & 15, kc = (l >> 4) * 8;

  for (int k0 = 0; k0 < K; k0 += 32) {
#pragma unroll
    for (int r = 0; r < 2; ++r) {
      gload_lds16(A + (size_t)(row0 + r * 64 + srow) * K + k0 + scol,
                  &lA[(r * 64 + srow) * 32 + scol]);
      gload_lds16(Bm + (size_t)(col0 + r * 64 + srow) * K + k0 + scol,
                  &lB[(r * 64 + srow) * 32 + scol]);
    }
    __syncthreads();
    bf16x8 af[4], bfr[4];
#pragma unroll
    for (int m = 0; m < 4; ++m)
      af[m] = *(const bf16x8*)&lA[(wr * 64 + m * 16 + lr) * 32 + kc];
#pragma unroll
    for (int n = 0; n < 4; ++n)
      bfr[n] = *(const bf16x8*)&lB[(wc * 64 + n * 16 + lr) * 32 + kc];
#pragma unroll
    for (int m = 0; m < 4; ++m)
#pragma unroll
      for (int n = 0; n < 4; ++n)
        acc[m][n] = __builtin_amdgcn_mfma_f32_16x16x32_bf16(af[m], bfr[n], acc[m][n], 0, 0, 0);
    __syncthreads();
  }

#pragma unroll
  for (int m = 0; m < 4; ++m) {
    const int row = row0 + wr * 64 + m * 16 + (l >> 4) * 4;
#pragma unroll
    for (int n = 0; n < 4; ++n) {
      const int col = col0 + wc * 64 + n * 16 + (l & 15);
      if (OUT_F32) {
        const float bv = bias[col];
#pragma unroll
        for (int j = 0; j < 4; ++j)
          Cf[(size_t)(row + j) * Nc + col] = acc[m][n][j] + bv;
      } else {
#pragma unroll
        for (int j = 0; j < 4; ++j)
          Cb[(size_t)(row + j) * Nc + col] = f2bf(acc[m][n][j]);
      }
    }
  }
}

// V slice of qkv (b,n,768 + h*64 + d) -> VT[(b*H+h), d, n]  (bf16)
__global__ void k_vtrans(const unsigned short* __restrict__ qkv, unsigned short* __restrict__ vt)
{
  __shared__ unsigned short tile[64][76];
  const int bh = blockIdx.x;
  const int b = bh / NH, h = bh - b * NH;
  const int n0 = blockIdx.y * 64;
  const int t = threadIdx.x;
  const int rr0 = t >> 4;
  const int c4 = (t & 15) * 4;
  const unsigned short* src = qkv + (size_t)(b * SEQ + n0) * QKVN + 2 * CDIM + h * HD;
#pragma unroll
  for (int rr = 0; rr < 4; ++rr) {
    int n = rr * 16 + rr0;
    ushort4v v = *(const ushort4v*)(src + (size_t)n * QKVN + c4);
    *(ushort4v*)&tile[n][c4] = v;
  }
  __syncthreads();
  unsigned short* dst = vt + (size_t)bh * HD * SEQ + n0;
#pragma unroll
  for (int rr = 0; rr < 4; ++rr) {
    int d = rr * 16 + rr0;
    ushort4v v;
    v.x = tile[c4 + 0][d];
    v.y = tile[c4 + 1][d];
    v.z = tile[c4 + 2][d];
    v.w = tile[c4 + 3][d];
    *(ushort4v*)(dst + (size_t)d * SEQ + c4) = v;
  }
}

// Flash attention v2: 1536 linear blocks, XCD-chunked swizzle, 4 waves/block,
// KT=64 K/V tiles double-buffered in LDS (XOR-swizzled granules), 1 barrier/iter.
__global__ __launch_bounds__(256, 3) void k_attn(
    const unsigned short* __restrict__ qkv, const float* __restrict__ mask,
    const unsigned short* __restrict__ vt, unsigned short* __restrict__ aout)
{
  // XCD-chunked bijective swizzle: 1536 blocks = 8 XCDs x 192
  const int bid = blockIdx.x;
  const int swz = (bid & 7) * 192 + (bid >> 3);
  const int bh = swz >> 5;          // 0..47
  const int nt = swz & 31;          // 0..31
  const int b = bh / NH, h = bh - b * NH;
  const int w = threadIdx.x >> 6, l = threadIdx.x & 63;
  const int gk = l >> 4, c = l & 15;   // frag coords: k-chunk group, col
  const int q0 = nt * 64 + w * 16;

  // LDS: K tile [64 keys][64 d], V^T tile [64 d][64 n], both granule-XOR-swizzled
  __shared__ unsigned short lK[2][4096];
  __shared__ unsigned short lV[2][4096];
  __shared__ unsigned short lP[4][16 * 72];
  unsigned short* pw = lP[w];

  const unsigned short* qb = qkv + (size_t)(b * SEQ + q0) * QKVN + h * HD;
  const unsigned short* kb = qkv + (size_t)(b * SEQ) * QKVN + CDIM + h * HD;
  const unsigned short* vb = vt + (size_t)bh * HD * SEQ;
  const float* mrow = mask + ((size_t)b * SEQ + q0) * SEQ;

  // staging address precompute: lane covers linear LDS bytes (w*2048 + j*1024 + l*16)
  // row = w*16 + j*8 + (l>>3); phys granule = l&7; logical granule = phys ^ (row&7)
  const int lrow = l >> 3, lg = l & 7;
  const int glog = lg ^ lrow;  // row&7 == lrow
  size_t kSrcOff[2], vSrcOff[2];
#pragma unroll
  for (int j = 0; j < 2; ++j) {
    const int row = w * 16 + j * 8 + lrow;
    kSrcOff[j] = (size_t)row * QKVN + glog * 8;
    vSrcOff[j] = (size_t)row * SEQ + glog * 8;
  }
  // fragment ds_read offsets (elems): row=16*blk + c, granule (4h+gk)^(c&7)
  const int fr0 = c * 64 + ((gk) ^ (c & 7)) * 8;
  const int fr1 = c * 64 + ((4 + gk) ^ (c & 7)) * 8;

  // Q fragments, pre-scaled by 1/sqrt(D)=0.125 (exact exponent shift)
  bf16x8 qf0 = *(const bf16x8*)(qb + (size_t)c * QKVN + gk * 8);
  bf16x8 qf1 = *(const bf16x8*)(qb + (size_t)c * QKVN + 32 + gk * 8);
#pragma unroll
  for (int i = 0; i < 8; ++i) {
    qf0[i] = (__bf16)((float)qf0[i] * 0.125f);
    qf1[i] = (__bf16)((float)qf1[i] * 0.125f);
  }

  const f32x4 vzero = {0.f, 0.f, 0.f, 0.f};
  f32x4 acco[4];
  float mreg[4], lreg[4];
#pragma unroll
  for (int r = 0; r < 4; ++r) { mreg[r] = -INFINITY; lreg[r] = 0.f; }
#pragma unroll
  for (int dt = 0; dt < 4; ++dt) acco[dt] = vzero;

  // prologue: stage kt=0 into buf 0
#pragma unroll
  for (int j = 0; j < 2; ++j) {
    gload_lds16(kb + kSrcOff[j], &lK[0][w * 1024 + j * 512]);
    gload_lds16(vb + vSrcOff[j], &lV[0][w * 1024 + j * 512]);
  }
  int buf = 0;

  for (int kt = 0; kt < SEQ; kt += 64) {
    __syncthreads();  // staged buf ready; prev iter's reads of buf^1 done
    if (kt + 64 < SEQ) {
      const int nk = kt + 64;
#pragma unroll
      for (int j = 0; j < 2; ++j) {
        gload_lds16(kb + (size_t)nk * QKVN + kSrcOff[j], &lK[buf ^ 1][w * 1024 + j * 512]);
        gload_lds16(vb + nk + vSrcOff[j], &lV[buf ^ 1][w * 1024 + j * 512]);
      }
    }
    // mask prefetch (fp32, read once)
    float mk[4][4];
#pragma unroll
    for (int j = 0; j < 4; ++j)
#pragma unroll
      for (int r = 0; r < 4; ++r)
        mk[j][r] = mrow[(size_t)(4 * gk + r) * SEQ + kt + 16 * j + c];

    // QK^T: S[q=4gk+r][key=16j+c]
    f32x4 s[4];
#pragma unroll
    for (int j = 0; j < 4; ++j) {
      bf16x8 kfa = *(const bf16x8*)&lK[buf][j * 1024 + fr0];
      bf16x8 kfb = *(const bf16x8*)&lK[buf][j * 1024 + fr1];
      s[j] = __builtin_amdgcn_mfma_f32_16x16x32_bf16(qf0, kfa, vzero, 0, 0, 0);
      s[j] = __builtin_amdgcn_mfma_f32_16x16x32_bf16(qf1, kfb, s[j], 0, 0, 0);
    }

    // masked scores + online softmax over 64 keys
    float x[4][4], tm[4];
#pragma unroll
    for (int j = 0; j < 4; ++j)
#pragma unroll
      for (int r = 0; r < 4; ++r)
        x[j][r] = fmaf(mk[j][r], -100000.0f, s[j][r]);
#pragma unroll
    for (int r = 0; r < 4; ++r)
      tm[r] = fmaxf(fmaxf(x[0][r], x[1][r]), fmaxf(x[2][r], x[3][r]));
#pragma unroll
    for (int off = 1; off < 16; off <<= 1)
#pragma unroll
      for (int r = 0; r < 4; ++r)
        tm[r] = fmaxf(tm[r], __shfl_xor(tm[r], off));

    float p[4][4], rs[4], al[4];
#pragma unroll
    for (int r = 0; r < 4; ++r) {
      const float mn = fmaxf(mreg[r], tm[r]);
      al[r] = __expf(mreg[r] - mn);
      mreg[r] = mn;
    }
#pragma unroll
    for (int j = 0; j < 4; ++j)
#pragma unroll
      for (int r = 0; r < 4; ++r)
        p[j][r] = __expf(x[j][r] - mreg[r]);
#pragma unroll
    for (int r = 0; r < 4; ++r)
      rs[r] = (p[0][r] + p[1][r]) + (p[2][r] + p[3][r]);
#pragma unroll
    for (int off = 1; off < 16; off <<= 1)
#pragma unroll
      for (int r = 0; r < 4; ++r)
        rs[r] += __shfl_xor(rs[r], off);
#pragma unroll
    for (int r = 0; r < 4; ++r)
      lreg[r] = lreg[r] * al[r] + rs[r];
#pragma unroll
    for (int dt = 0; dt < 4; ++dt)
#pragma unroll
      for (int r = 0; r < 4; ++r)
        acco[dt][r] *= al[r];

    // P (16 q x 64 key) via wave-private LDS transpose
    __asm__ volatile("" ::: "memory");
#pragma unroll
    for (int j = 0; j < 4; ++j)
#pragma unroll
      for (int r = 0; r < 4; ++r)
        pw[(4 * gk + r) * 72 + 16 * j + c] = f2bf(p[j][r]);
    __asm__ volatile("" ::: "memory");
    bf16x8 pf0 = *(const bf16x8*)&pw[c * 72 + gk * 8];
    bf16x8 pf1 = *(const bf16x8*)&pw[c * 72 + 32 + gk * 8];

    // PV: O[q][d=16dt+c] += P * V
#pragma unroll
    for (int dt = 0; dt < 4; ++dt) {
      bf16x8 vf0 = *(const bf16x8*)&lV[buf][dt * 1024 + fr0];
      bf16x8 vf1 = *(const bf16x8*)&lV[buf][dt * 1024 + fr1];
      acco[dt] = __builtin_amdgcn_mfma_f32_16x16x32_bf16(pf0, vf0, acco[dt], 0, 0, 0);
      acco[dt] = __builtin_amdgcn_mfma_f32_16x16x32_bf16(pf1, vf1, acco[dt], 0, 0, 0);
    }
    buf ^= 1;
  }

  // out (B,N,C) bf16: row q0+4gk+r, col h*64 + dt*16 + c
  unsigned short* ob = aout + (size_t)(b * SEQ + q0) * CDIM + h * HD;
#pragma unroll
  for (int r = 0; r < 4; ++r) {
    const float inv = 1.0f / lreg[r];
#pragma unroll
    for (int dt = 0; dt < 4; ++dt)
      ob[(size_t)(4 * gk + r) * CDIM + dt * 16 + c] = f2bf(acco[dt][r] * inv);
  }
}

extern "C" void kernel_launch(void* const* d_in, const int* in_sizes, int n_in,
                              void* d_out, int out_size, void* d_ws, size_t ws_size,
                              hipStream_t stream) {
  (void)in_sizes; (void)n_in; (void)out_size; (void)ws_size;
  const float* x      = (const float*)d_in[0];
  const float* mask   = (const float*)d_in[2];
  const float* qkv_w  = (const float*)d_in[3];
  const float* proj_w = (const float*)d_in[4];
  const float* proj_b = (const float*)d_in[5];
  float* out = (float*)d_out;
  char* ws = (char*)d_ws;

  unsigned short* xb    = (unsigned short*)(ws + 0);         // x bf16:      12,582,912
  unsigned short* wqb   = (unsigned short*)(ws + 12582912);  // qkv_w bf16:     884,736
  unsigned short* wpb   = (unsigned short*)(ws + 13467648);  // proj_w bf16:    294,912
  unsigned short* qkvb  = (unsigned short*)(ws + 13762560);  // qkv bf16:    37,748,736
  unsigned short* vtb   = (unsigned short*)(ws + 51511296);  // V^T bf16:    12,582,912
  unsigned short* aoutb = (unsigned short*)(ws + 64094208);  // attn out:    12,582,912

  k_convert<<<6144, 256, 0, stream>>>(x, xb, 1572864);
  k_convert<<<432, 256, 0, stream>>>(qkv_w, wqb, 110592);
  k_convert<<<144, 256, 0, stream>>>(proj_w, wpb, 36864);
  k_gemm_bt<0><<<dim3(128, 9), 256, 0, stream>>>(xb, wqb, qkvb, nullptr, nullptr, 16384, 1152, 384);
  k_vtrans<<<dim3(48, 32), 256, 0, stream>>>(qkvb, vtb);
  k_attn<<<1536, 256, 0, stream>>>(qkvb, mask, vtb, aoutb);
  k_gemm_bt<1><<<dim3(128, 3), 256, 0, stream>>>(aoutb, wpb, nullptr, out, proj_b, 16384, 384, 384);
}

// Round 3
// 228.161 us; speedup vs baseline: 1.8912x; 1.0199x over previous
//
#include <hip/hip_runtime.h>
#include <stdint.h>
#include <math.h>

#define BB 8
#define SEQ 2048
#define CDIM 384
#define NH 6
#define HD 64
#define QKVN 1152

typedef __attribute__((ext_vector_type(8))) __bf16 bf16x8;
typedef __attribute__((ext_vector_type(4))) float f32x4;
typedef __attribute__((ext_vector_type(4))) unsigned short ushort4v;

__device__ __forceinline__ unsigned short f2bf(float f) {
  unsigned int u = __float_as_uint(f);
  u += 0x7fffu + ((u >> 16) & 1u);
  return (unsigned short)(u >> 16);
}

// fp32 -> bf16 conversion, 4 elems/thread
__global__ void k_convert(const float* __restrict__ src, unsigned short* __restrict__ dst, int n4) {
  int i = blockIdx.x * blockDim.x + threadIdx.x;
  if (i >= n4) return;
  float4 f = reinterpret_cast<const float4*>(src)[i];
  ushort4v u;
  u.x = f2bf(f.x); u.y = f2bf(f.y); u.z = f2bf(f.z); u.w = f2bf(f.w);
  reinterpret_cast<ushort4v*>(dst)[i] = u;
}

__device__ __forceinline__ void gload_lds16(const unsigned short* g, unsigned short* l) {
  __builtin_amdgcn_global_load_lds((const __attribute__((address_space(1))) void*)g,
                                   (__attribute__((address_space(3))) void*)l, 16, 0, 0);
}

// C[M,Nc] = A[M,K] * Bm[Nc,K]^T   (both row-major bf16, K contiguous; m97 structure)
template<int OUT_F32>
__global__ __launch_bounds__(256, 2) void k_gemm_bt(
    const unsigned short* __restrict__ A, const unsigned short* __restrict__ Bm,
    unsigned short* __restrict__ Cb, float* __restrict__ Cf,
    const float* __restrict__ bias, int M, int Nc, int K)
{
  __shared__ unsigned short lA[128 * 32];
  __shared__ unsigned short lB[128 * 32];
  const int t = threadIdx.x;
  const int w = t >> 6, l = t & 63;
  const int wr = w >> 1, wc = w & 1;
  const int row0 = blockIdx.x * 128, col0 = blockIdx.y * 128;
  const f32x4 vzero = {0.f, 0.f, 0.f, 0.f};
  f32x4 acc[4][4];
#pragma unroll
  for (int m = 0; m < 4; ++m)
#pragma unroll
    for (int n = 0; n < 4; ++n) acc[m][n] = vzero;

  const int srow = w * 16 + (l >> 2);
  const int scol = (l & 3) * 8;
  const int lr = l & 15, kc = (l >> 4) * 8;

  for (int k0 = 0; k0 < K; k0 += 32) {
#pragma unroll
    for (int r = 0; r < 2; ++r) {
      gload_lds16(A + (size_t)(row0 + r * 64 + srow) * K + k0 + scol,
                  &lA[(r * 64 + srow) * 32 + scol]);
      gload_lds16(Bm + (size_t)(col0 + r * 64 + srow) * K + k0 + scol,
                  &lB[(r * 64 + srow) * 32 + scol]);
    }
    __syncthreads();
    bf16x8 af[4], bfr[4];
#pragma unroll
    for (int m = 0; m < 4; ++m)
      af[m] = *(const bf16x8*)&lA[(wr * 64 + m * 16 + lr) * 32 + kc];
#pragma unroll
    for (int n = 0; n < 4; ++n)
      bfr[n] = *(const bf16x8*)&lB[(wc * 64 + n * 16 + lr) * 32 + kc];
#pragma unroll
    for (int m = 0; m < 4; ++m)
#pragma unroll
      for (int n = 0; n < 4; ++n)
        acc[m][n] = __builtin_amdgcn_mfma_f32_16x16x32_bf16(af[m], bfr[n], acc[m][n], 0, 0, 0);
    __syncthreads();
  }

#pragma unroll
  for (int m = 0; m < 4; ++m) {
    const int row = row0 + wr * 64 + m * 16 + (l >> 4) * 4;
#pragma unroll
    for (int n = 0; n < 4; ++n) {
      const int col = col0 + wc * 64 + n * 16 + (l & 15);
      if (OUT_F32) {
        const float bv = bias[col];
#pragma unroll
        for (int j = 0; j < 4; ++j)
          Cf[(size_t)(row + j) * Nc + col] = acc[m][n][j] + bv;
      } else {
#pragma unroll
        for (int j = 0; j < 4; ++j)
          Cb[(size_t)(row + j) * Nc + col] = f2bf(acc[m][n][j]);
      }
    }
  }
}

// V slice of qkv (b,n,768 + h*64 + d) -> VT[(b*H+h), d, n]  (bf16)
__global__ void k_vtrans(const unsigned short* __restrict__ qkv, unsigned short* __restrict__ vt)
{
  __shared__ unsigned short tile[64][76];
  const int bh = blockIdx.x;
  const int b = bh / NH, h = bh - b * NH;
  const int n0 = blockIdx.y * 64;
  const int t = threadIdx.x;
  const int rr0 = t >> 4;
  const int c4 = (t & 15) * 4;
  const unsigned short* src = qkv + (size_t)(b * SEQ + n0) * QKVN + 2 * CDIM + h * HD;
#pragma unroll
  for (int rr = 0; rr < 4; ++rr) {
    int n = rr * 16 + rr0;
    ushort4v v = *(const ushort4v*)(src + (size_t)n * QKVN + c4);
    *(ushort4v*)&tile[n][c4] = v;
  }
  __syncthreads();
  unsigned short* dst = vt + (size_t)bh * HD * SEQ + n0;
#pragma unroll
  for (int rr = 0; rr < 4; ++rr) {
    int d = rr * 16 + rr0;
    ushort4v v;
    v.x = tile[c4 + 0][d];
    v.y = tile[c4 + 1][d];
    v.z = tile[c4 + 2][d];
    v.w = tile[c4 + 3][d];
    *(ushort4v*)(dst + (size_t)d * SEQ + c4) = v;
  }
}

// Flash attention v3: 768 blocks x 8 waves, batch->XCD mapping (b = bid&7),
// KT=64 double-buffered K/V LDS, log2-domain softmax, MFMA-ones rowsum,
// defer-rescale (T13, thr=8 log2).
__global__ __launch_bounds__(512, 6) void k_attn(
    const unsigned short* __restrict__ qkv, const float* __restrict__ mask,
    const unsigned short* __restrict__ vt, unsigned short* __restrict__ aout)
{
  const int bid = blockIdx.x;
  const int b = bid & 7;            // batch -> XCD
  const int g2 = bid >> 3;          // 0..95
  const int h = g2 % NH;            // head fastest: 6 heads of same (b,nt) co-resident
  const int nt = g2 / NH;           // 0..15
  const int t = threadIdx.x;
  const int w = t >> 6, l = t & 63;
  const int gk = l >> 4, c = l & 15;
  const int q0 = nt * 128 + w * 16;

  __shared__ unsigned short lK[2][4096];
  __shared__ unsigned short lV[2][4096];
  __shared__ __bf16 lP[8][16 * 72];
  __bf16* pw = lP[w];

  const unsigned short* qb = qkv + (size_t)(b * SEQ + q0) * QKVN + h * HD;
  const unsigned short* kb = qkv + (size_t)(b * SEQ) * QKVN + CDIM + h * HD;
  const unsigned short* vb = vt + (size_t)(b * NH + h) * HD * SEQ;
  const float* mrow = mask + ((size_t)b * SEQ + q0) * SEQ;

  // staging: 512 threads x 16B = one full 64x64 bf16 tile per issue.
  // row = t>>3, phys granule = t&7, logical granule = phys ^ (row&7)
  const int trow = t >> 3, tg = t & 7;
  const int glog = tg ^ (trow & 7);
  const size_t kSrc = (size_t)trow * QKVN + glog * 8;
  const size_t vSrc = (size_t)trow * SEQ + glog * 8;
  const int tid8 = t * 8;  // ushort index of this thread's 16B LDS slot

  // fragment ds_read offsets (elems): row 16j+c, phys granule gk^(c&7) / (4+gk)^(c&7)
  const int fr0 = c * 64 + ((gk) ^ (c & 7)) * 8;
  const int fr1 = c * 64 + ((4 + gk) ^ (c & 7)) * 8;

  // Q fragments, pre-scaled by (1/sqrt(D)) * log2(e) -> scores in log2 domain
  bf16x8 qf0 = *(const bf16x8*)(qb + (size_t)c * QKVN + gk * 8);
  bf16x8 qf1 = *(const bf16x8*)(qb + (size_t)c * QKVN + 32 + gk * 8);
#pragma unroll
  for (int i = 0; i < 8; ++i) {
    qf0[i] = (__bf16)((float)qf0[i] * 0.18033688f);
    qf1[i] = (__bf16)((float)qf1[i] * 0.18033688f);
  }

  const __bf16 one = (__bf16)1.0f;
  const bf16x8 vones = {one, one, one, one, one, one, one, one};
  const f32x4 vzero = {0.f, 0.f, 0.f, 0.f};
  f32x4 acco[4];
  f32x4 asum = vzero;
  float mreg[4];
#pragma unroll
  for (int r = 0; r < 4; ++r) mreg[r] = -INFINITY;
#pragma unroll
  for (int dt = 0; dt < 4; ++dt) acco[dt] = vzero;

  // prologue: stage kt=0 into buf 0
  gload_lds16(kb + kSrc, &lK[0][tid8]);
  gload_lds16(vb + vSrc, &lV[0][tid8]);
  int buf = 0;

  for (int kt = 0; kt < SEQ; kt += 64) {
    __syncthreads();
    if (kt + 64 < SEQ) {
      gload_lds16(kb + (size_t)(kt + 64) * QKVN + kSrc, &lK[buf ^ 1][tid8]);
      gload_lds16(vb + (kt + 64) + vSrc, &lV[buf ^ 1][tid8]);
    }
    // mask prefetch (fp32, mandatory traffic)
    float mk[4][4];
#pragma unroll
    for (int j = 0; j < 4; ++j)
#pragma unroll
      for (int r = 0; r < 4; ++r)
        mk[j][r] = mrow[(size_t)(4 * gk + r) * SEQ + kt + 16 * j + c];

    // QK^T (log2 domain): S[q=4gk+r][key=16j+c]
    f32x4 s[4];
#pragma unroll
    for (int j = 0; j < 4; ++j) {
      bf16x8 kfa = *(const bf16x8*)&lK[buf][j * 1024 + fr0];
      bf16x8 kfb = *(const bf16x8*)&lK[buf][j * 1024 + fr1];
      s[j] = __builtin_amdgcn_mfma_f32_16x16x32_bf16(qf0, kfa, vzero, 0, 0, 0);
      s[j] = __builtin_amdgcn_mfma_f32_16x16x32_bf16(qf1, kfb, s[j], 0, 0, 0);
    }

    // masked log2-scores
    float x[4][4], tm[4];
#pragma unroll
    for (int j = 0; j < 4; ++j)
#pragma unroll
      for (int r = 0; r < 4; ++r)
        x[j][r] = fmaf(mk[j][r], -144269.50f, s[j][r]);  // -1e5 * log2(e)
#pragma unroll
    for (int r = 0; r < 4; ++r)
      tm[r] = fmaxf(fmaxf(fmaxf(x[0][r], x[1][r]), x[2][r]), x[3][r]);
#pragma unroll
    for (int off = 1; off < 16; off <<= 1)
#pragma unroll
      for (int r = 0; r < 4; ++r)
        tm[r] = fmaxf(tm[r], __shfl_xor(tm[r], off));

    // defer-rescale: only rescale when some row's max grew past threshold
    bool nd = (tm[0] > mreg[0] + 8.f) || (tm[1] > mreg[1] + 8.f) ||
              (tm[2] > mreg[2] + 8.f) || (tm[3] > mreg[3] + 8.f);
    if (__any(nd)) {
#pragma unroll
      for (int r = 0; r < 4; ++r) {
        const float mn = fmaxf(mreg[r], tm[r]);
        const float al = __builtin_amdgcn_exp2f(mreg[r] - mn);
        mreg[r] = mn;
        asum[r] *= al;
#pragma unroll
        for (int dt = 0; dt < 4; ++dt) acco[dt][r] *= al;
      }
    }

    // P = exp2(x - m) -> LDS transpose (wave-private)
    __asm__ volatile("" ::: "memory");
#pragma unroll
    for (int j = 0; j < 4; ++j)
#pragma unroll
      for (int r = 0; r < 4; ++r)
        pw[(4 * gk + r) * 72 + 16 * j + c] = (__bf16)__builtin_amdgcn_exp2f(x[j][r] - mreg[r]);
    __asm__ volatile("" ::: "memory");
    bf16x8 pf0 = *(const bf16x8*)&pw[c * 72 + gk * 8];
    bf16x8 pf1 = *(const bf16x8*)&pw[c * 72 + 32 + gk * 8];

    // PV + MFMA-ones rowsum
#pragma unroll
    for (int dt = 0; dt < 4; ++dt) {
      bf16x8 vf0 = *(const bf16x8*)&lV[buf][dt * 1024 + fr0];
      bf16x8 vf1 = *(const bf16x8*)&lV[buf][dt * 1024 + fr1];
      acco[dt] = __builtin_amdgcn_mfma_f32_16x16x32_bf16(pf0, vf0, acco[dt], 0, 0, 0);
      acco[dt] = __builtin_amdgcn_mfma_f32_16x16x32_bf16(pf1, vf1, acco[dt], 0, 0, 0);
    }
    asum = __builtin_amdgcn_mfma_f32_16x16x32_bf16(pf0, vones, asum, 0, 0, 0);
    asum = __builtin_amdgcn_mfma_f32_16x16x32_bf16(pf1, vones, asum, 0, 0, 0);
    buf ^= 1;
  }

  // out (B,N,C) bf16: row q0+4gk+r, col h*64 + dt*16 + c
  unsigned short* ob = aout + (size_t)(b * SEQ + q0) * CDIM + h * HD;
#pragma unroll
  for (int r = 0; r < 4; ++r) {
    const float inv = 1.0f / asum[r];
#pragma unroll
    for (int dt = 0; dt < 4; ++dt)
      ob[(size_t)(4 * gk + r) * CDIM + dt * 16 + c] = f2bf(acco[dt][r] * inv);
  }
}

extern "C" void kernel_launch(void* const* d_in, const int* in_sizes, int n_in,
                              void* d_out, int out_size, void* d_ws, size_t ws_size,
                              hipStream_t stream) {
  (void)in_sizes; (void)n_in; (void)out_size; (void)ws_size;
  const float* x      = (const float*)d_in[0];
  const float* mask   = (const float*)d_in[2];
  const float* qkv_w  = (const float*)d_in[3];
  const float* proj_w = (const float*)d_in[4];
  const float* proj_b = (const float*)d_in[5];
  float* out = (float*)d_out;
  char* ws = (char*)d_ws;

  unsigned short* xb    = (unsigned short*)(ws + 0);         // x bf16:      12,582,912
  unsigned short* wqb   = (unsigned short*)(ws + 12582912);  // qkv_w bf16:     884,736
  unsigned short* wpb   = (unsigned short*)(ws + 13467648);  // proj_w bf16:    294,912
  unsigned short* qkvb  = (unsigned short*)(ws + 13762560);  // qkv bf16:    37,748,736
  unsigned short* vtb   = (unsigned short*)(ws + 51511296);  // V^T bf16:    12,582,912
  unsigned short* aoutb = (unsigned short*)(ws + 64094208);  // attn out:    12,582,912

  k_convert<<<6144, 256, 0, stream>>>(x, xb, 1572864);
  k_convert<<<432, 256, 0, stream>>>(qkv_w, wqb, 110592);
  k_convert<<<144, 256, 0, stream>>>(proj_w, wpb, 36864);
  k_gemm_bt<0><<<dim3(128, 9), 256, 0, stream>>>(xb, wqb, qkvb, nullptr, nullptr, 16384, 1152, 384);
  k_vtrans<<<dim3(48, 32), 256, 0, stream>>>(qkvb, vtb);
  k_attn<<<768, 512, 0, stream>>>(qkvb, mask, vtb, aoutb);
  k_gemm_bt<1><<<dim3(128, 3), 256, 0, stream>>>(aoutb, wpb, nullptr, out, proj_b, 16384, 384, 384);
}

// Round 4
// 193.470 us; speedup vs baseline: 2.2303x; 1.1793x over previous
//
#include <hip/hip_runtime.h>
#include <stdint.h>
#include <math.h>

#define BB 8
#define SEQ 2048
#define CDIM 384
#define NH 6
#define HD 64
#define QKVN 1152

typedef __attribute__((ext_vector_type(8))) __bf16 bf16x8;
typedef __attribute__((ext_vector_type(4))) float f32x4;
typedef __attribute__((ext_vector_type(4))) unsigned short ushort4v;

__device__ __forceinline__ unsigned short f2bf(float f) {
  unsigned int u = __float_as_uint(f);
  u += 0x7fffu + ((u >> 16) & 1u);
  return (unsigned short)(u >> 16);
}

// fp32 -> bf16 conversion, 4 elems/thread
__global__ void k_convert(const float* __restrict__ src, unsigned short* __restrict__ dst, int n4) {
  int i = blockIdx.x * blockDim.x + threadIdx.x;
  if (i >= n4) return;
  float4 f = reinterpret_cast<const float4*>(src)[i];
  ushort4v u;
  u.x = f2bf(f.x); u.y = f2bf(f.y); u.z = f2bf(f.z); u.w = f2bf(f.w);
  reinterpret_cast<ushort4v*>(dst)[i] = u;
}

__device__ __forceinline__ void gload_lds16(const unsigned short* g, unsigned short* l) {
  __builtin_amdgcn_global_load_lds((const __attribute__((address_space(1))) void*)g,
                                   (__attribute__((address_space(3))) void*)l, 16, 0, 0);
}

// C[M,Nc] = A[M,K] * Bm[Nc,K]^T   (both row-major bf16, K contiguous; m97 structure)
template<int OUT_F32>
__global__ __launch_bounds__(256, 2) void k_gemm_bt(
    const unsigned short* __restrict__ A, const unsigned short* __restrict__ Bm,
    unsigned short* __restrict__ Cb, float* __restrict__ Cf,
    const float* __restrict__ bias, int M, int Nc, int K)
{
  __shared__ unsigned short lA[128 * 32];
  __shared__ unsigned short lB[128 * 32];
  const int t = threadIdx.x;
  const int w = t >> 6, l = t & 63;
  const int wr = w >> 1, wc = w & 1;
  const int row0 = blockIdx.x * 128, col0 = blockIdx.y * 128;
  const f32x4 vzero = {0.f, 0.f, 0.f, 0.f};
  f32x4 acc[4][4];
#pragma unroll
  for (int m = 0; m < 4; ++m)
#pragma unroll
    for (int n = 0; n < 4; ++n) acc[m][n] = vzero;

  const int srow = w * 16 + (l >> 2);
  const int scol = (l & 3) * 8;
  const int lr = l & 15, kc = (l >> 4) * 8;

  for (int k0 = 0; k0 < K; k0 += 32) {
#pragma unroll
    for (int r = 0; r < 2; ++r) {
      gload_lds16(A + (size_t)(row0 + r * 64 + srow) * K + k0 + scol,
                  &lA[(r * 64 + srow) * 32 + scol]);
      gload_lds16(Bm + (size_t)(col0 + r * 64 + srow) * K + k0 + scol,
                  &lB[(r * 64 + srow) * 32 + scol]);
    }
    __syncthreads();
    bf16x8 af[4], bfr[4];
#pragma unroll
    for (int m = 0; m < 4; ++m)
      af[m] = *(const bf16x8*)&lA[(wr * 64 + m * 16 + lr) * 32 + kc];
#pragma unroll
    for (int n = 0; n < 4; ++n)
      bfr[n] = *(const bf16x8*)&lB[(wc * 64 + n * 16 + lr) * 32 + kc];
#pragma unroll
    for (int m = 0; m < 4; ++m)
#pragma unroll
      for (int n = 0; n < 4; ++n)
        acc[m][n] = __builtin_amdgcn_mfma_f32_16x16x32_bf16(af[m], bfr[n], acc[m][n], 0, 0, 0);
    __syncthreads();
  }

#pragma unroll
  for (int m = 0; m < 4; ++m) {
    const int row = row0 + wr * 64 + m * 16 + (l >> 4) * 4;
#pragma unroll
    for (int n = 0; n < 4; ++n) {
      const int col = col0 + wc * 64 + n * 16 + (l & 15);
      if (OUT_F32) {
        const float bv = bias[col];
#pragma unroll
        for (int j = 0; j < 4; ++j)
          Cf[(size_t)(row + j) * Nc + col] = acc[m][n][j] + bv;
      } else {
#pragma unroll
        for (int j = 0; j < 4; ++j)
          Cb[(size_t)(row + j) * Nc + col] = f2bf(acc[m][n][j]);
      }
    }
  }
}

// V slice of qkv (b,n,768 + h*64 + d) -> VT[(b*H+h), d, n]  (bf16)
__global__ void k_vtrans(const unsigned short* __restrict__ qkv, unsigned short* __restrict__ vt)
{
  __shared__ unsigned short tile[64][76];
  const int bh = blockIdx.x;
  const int b = bh / NH, h = bh - b * NH;
  const int n0 = blockIdx.y * 64;
  const int t = threadIdx.x;
  const int rr0 = t >> 4;
  const int c4 = (t & 15) * 4;
  const unsigned short* src = qkv + (size_t)(b * SEQ + n0) * QKVN + 2 * CDIM + h * HD;
#pragma unroll
  for (int rr = 0; rr < 4; ++rr) {
    int n = rr * 16 + rr0;
    ushort4v v = *(const ushort4v*)(src + (size_t)n * QKVN + c4);
    *(ushort4v*)&tile[n][c4] = v;
  }
  __syncthreads();
  unsigned short* dst = vt + (size_t)bh * HD * SEQ + n0;
#pragma unroll
  for (int rr = 0; rr < 4; ++rr) {
    int d = rr * 16 + rr0;
    ushort4v v;
    v.x = tile[c4 + 0][d];
    v.y = tile[c4 + 1][d];
    v.z = tile[c4 + 2][d];
    v.w = tile[c4 + 3][d];
    *(ushort4v*)(dst + (size_t)d * SEQ + c4) = v;
  }
}

// Flash attention v4: 768 blocks x 8 waves, batch->XCD mapping (b = bid&7),
// KT=64 double-buffered K/V LDS, log2-domain softmax, MFMA-ones rowsum,
// defer-rescale, mask prefetch double-buffer. launch_bounds(512,4): no spill.
__global__ __launch_bounds__(512, 4) void k_attn(
    const unsigned short* __restrict__ qkv, const float* __restrict__ mask,
    const unsigned short* __restrict__ vt, unsigned short* __restrict__ aout)
{
  const int bid = blockIdx.x;
  const int b = bid & 7;            // batch -> XCD
  const int g2 = bid >> 3;          // 0..95
  const int h = g2 % NH;            // head fastest: 6 heads of same (b,nt) co-resident
  const int nt = g2 / NH;           // 0..15
  const int t = threadIdx.x;
  const int w = t >> 6, l = t & 63;
  const int gk = l >> 4, c = l & 15;
  const int q0 = nt * 128 + w * 16;

  __shared__ unsigned short lK[2][4096];
  __shared__ unsigned short lV[2][4096];
  __shared__ __bf16 lP[8][16 * 80];   // stride 80 elems (160B): 4-way read banks, 16B-aligned
  __bf16* pw = lP[w];

  const unsigned short* qb = qkv + (size_t)(b * SEQ + q0) * QKVN + h * HD;
  const unsigned short* kb = qkv + (size_t)(b * SEQ) * QKVN + CDIM + h * HD;
  const unsigned short* vb = vt + (size_t)(b * NH + h) * HD * SEQ;
  const float* mrow = mask + ((size_t)b * SEQ + q0) * SEQ;

  // staging: 512 threads x 16B = one full 64x64 bf16 tile per issue.
  const int trow = t >> 3, tg = t & 7;
  const int glog = tg ^ (trow & 7);
  const size_t kSrc = (size_t)trow * QKVN + glog * 8;
  const size_t vSrc = (size_t)trow * SEQ + glog * 8;
  const int tid8 = t * 8;

  // fragment ds_read offsets (elems)
  const int fr0 = c * 64 + ((gk) ^ (c & 7)) * 8;
  const int fr1 = c * 64 + ((4 + gk) ^ (c & 7)) * 8;

  // Q fragments, pre-scaled by (1/sqrt(D)) * log2(e) -> scores in log2 domain
  bf16x8 qf0 = *(const bf16x8*)(qb + (size_t)c * QKVN + gk * 8);
  bf16x8 qf1 = *(const bf16x8*)(qb + (size_t)c * QKVN + 32 + gk * 8);
#pragma unroll
  for (int i = 0; i < 8; ++i) {
    qf0[i] = (__bf16)((float)qf0[i] * 0.18033688f);
    qf1[i] = (__bf16)((float)qf1[i] * 0.18033688f);
  }

  const __bf16 one = (__bf16)1.0f;
  const bf16x8 vones = {one, one, one, one, one, one, one, one};
  const f32x4 vzero = {0.f, 0.f, 0.f, 0.f};
  f32x4 acco[4];
  f32x4 asum = vzero;
  float mreg[4];
#pragma unroll
  for (int r = 0; r < 4; ++r) mreg[r] = -INFINITY;
#pragma unroll
  for (int dt = 0; dt < 4; ++dt) acco[dt] = vzero;

  // prologue: stage kt=0 into buf 0; preload first mask tile
  gload_lds16(kb + kSrc, &lK[0][tid8]);
  gload_lds16(vb + vSrc, &lV[0][tid8]);
  float mk[4][4];
#pragma unroll
  for (int j = 0; j < 4; ++j)
#pragma unroll
    for (int r = 0; r < 4; ++r)
      mk[j][r] = mrow[(size_t)(4 * gk + r) * SEQ + 16 * j + c];
  int buf = 0;

  for (int kt = 0; kt < SEQ; kt += 64) {
    const bool haveNext = (kt + 64 < SEQ);
    __syncthreads();
    if (haveNext) {
      gload_lds16(kb + (size_t)(kt + 64) * QKVN + kSrc, &lK[buf ^ 1][tid8]);
      gload_lds16(vb + (kt + 64) + vSrc, &lV[buf ^ 1][tid8]);
    }

    // QK^T (log2 domain): S[q=4gk+r][key=16j+c]
    f32x4 s[4];
#pragma unroll
    for (int j = 0; j < 4; ++j) {
      bf16x8 kfa = *(const bf16x8*)&lK[buf][j * 1024 + fr0];
      bf16x8 kfb = *(const bf16x8*)&lK[buf][j * 1024 + fr1];
      s[j] = __builtin_amdgcn_mfma_f32_16x16x32_bf16(qf0, kfa, vzero, 0, 0, 0);
      s[j] = __builtin_amdgcn_mfma_f32_16x16x32_bf16(qf1, kfb, s[j], 0, 0, 0);
    }

    // prefetch next mask tile while MFMAs complete (drains at next barrier)
    float mk2[4][4];
    if (haveNext) {
#pragma unroll
      for (int j = 0; j < 4; ++j)
#pragma unroll
        for (int r = 0; r < 4; ++r)
          mk2[j][r] = mrow[(size_t)(4 * gk + r) * SEQ + kt + 64 + 16 * j + c];
    }

    // masked log2-scores (in place), running max
    float tm[4];
#pragma unroll
    for (int j = 0; j < 4; ++j)
#pragma unroll
      for (int r = 0; r < 4; ++r)
        s[j][r] = fmaf(mk[j][r], -144269.50f, s[j][r]);  // -1e5 * log2(e)
#pragma unroll
    for (int r = 0; r < 4; ++r)
      tm[r] = fmaxf(fmaxf(fmaxf(s[0][r], s[1][r]), s[2][r]), s[3][r]);
#pragma unroll
    for (int off = 1; off < 16; off <<= 1)
#pragma unroll
      for (int r = 0; r < 4; ++r)
        tm[r] = fmaxf(tm[r], __shfl_xor(tm[r], off));

    // defer-rescale (T13): only when some row's max grew past threshold
    bool nd = (tm[0] > mreg[0] + 8.f) || (tm[1] > mreg[1] + 8.f) ||
              (tm[2] > mreg[2] + 8.f) || (tm[3] > mreg[3] + 8.f);
    if (__any(nd)) {
#pragma unroll
      for (int r = 0; r < 4; ++r) {
        const float mn = fmaxf(mreg[r], tm[r]);
        const float al = __builtin_amdgcn_exp2f(mreg[r] - mn);
        mreg[r] = mn;
        asum[r] *= al;
#pragma unroll
        for (int dt = 0; dt < 4; ++dt) acco[dt][r] *= al;
      }
    }

    // P = exp2(s - m) -> LDS transpose (wave-private)
    __asm__ volatile("" ::: "memory");
#pragma unroll
    for (int j = 0; j < 4; ++j)
#pragma unroll
      for (int r = 0; r < 4; ++r)
        pw[(4 * gk + r) * 80 + 16 * j + c] = (__bf16)__builtin_amdgcn_exp2f(s[j][r] - mreg[r]);
    __asm__ volatile("" ::: "memory");
    bf16x8 pf0 = *(const bf16x8*)&pw[c * 80 + gk * 8];
    bf16x8 pf1 = *(const bf16x8*)&pw[c * 80 + 32 + gk * 8];

    // PV + MFMA-ones rowsum
#pragma unroll
    for (int dt = 0; dt < 4; ++dt) {
      bf16x8 vf0 = *(const bf16x8*)&lV[buf][dt * 1024 + fr0];
      bf16x8 vf1 = *(const bf16x8*)&lV[buf][dt * 1024 + fr1];
      acco[dt] = __builtin_amdgcn_mfma_f32_16x16x32_bf16(pf0, vf0, acco[dt], 0, 0, 0);
      acco[dt] = __builtin_amdgcn_mfma_f32_16x16x32_bf16(pf1, vf1, acco[dt], 0, 0, 0);
    }
    asum = __builtin_amdgcn_mfma_f32_16x16x32_bf16(pf0, vones, asum, 0, 0, 0);
    asum = __builtin_amdgcn_mfma_f32_16x16x32_bf16(pf1, vones, asum, 0, 0, 0);

    if (haveNext) {
#pragma unroll
      for (int j = 0; j < 4; ++j)
#pragma unroll
        for (int r = 0; r < 4; ++r)
          mk[j][r] = mk2[j][r];
    }
    buf ^= 1;
  }

  // out (B,N,C) bf16: row q0+4gk+r, col h*64 + dt*16 + c
  unsigned short* ob = aout + (size_t)(b * SEQ + q0) * CDIM + h * HD;
#pragma unroll
  for (int r = 0; r < 4; ++r) {
    const float inv = 1.0f / asum[r];
#pragma unroll
    for (int dt = 0; dt < 4; ++dt)
      ob[(size_t)(4 * gk + r) * CDIM + dt * 16 + c] = f2bf(acco[dt][r] * inv);
  }
}

extern "C" void kernel_launch(void* const* d_in, const int* in_sizes, int n_in,
                              void* d_out, int out_size, void* d_ws, size_t ws_size,
                              hipStream_t stream) {
  (void)in_sizes; (void)n_in; (void)out_size; (void)ws_size;
  const float* x      = (const float*)d_in[0];
  const float* mask   = (const float*)d_in[2];
  const float* qkv_w  = (const float*)d_in[3];
  const float* proj_w = (const float*)d_in[4];
  const float* proj_b = (const float*)d_in[5];
  float* out = (float*)d_out;
  char* ws = (char*)d_ws;

  unsigned short* xb    = (unsigned short*)(ws + 0);         // x bf16:      12,582,912
  unsigned short* wqb   = (unsigned short*)(ws + 12582912);  // qkv_w bf16:     884,736
  unsigned short* wpb   = (unsigned short*)(ws + 13467648);  // proj_w bf16:    294,912
  unsigned short* qkvb  = (unsigned short*)(ws + 13762560);  // qkv bf16:    37,748,736
  unsigned short* vtb   = (unsigned short*)(ws + 51511296);  // V^T bf16:    12,582,912
  unsigned short* aoutb = (unsigned short*)(ws + 64094208);  // attn out:    12,582,912

  k_convert<<<6144, 256, 0, stream>>>(x, xb, 1572864);
  k_convert<<<432, 256, 0, stream>>>(qkv_w, wqb, 110592);
  k_convert<<<144, 256, 0, stream>>>(proj_w, wpb, 36864);
  k_gemm_bt<0><<<dim3(128, 9), 256, 0, stream>>>(xb, wqb, qkvb, nullptr, nullptr, 16384, 1152, 384);
  k_vtrans<<<dim3(48, 32), 256, 0, stream>>>(qkvb, vtb);
  k_attn<<<768, 512, 0, stream>>>(qkvb, mask, vtb, aoutb);
  k_gemm_bt<1><<<dim3(128, 3), 256, 0, stream>>>(aoutb, wpb, nullptr, out, proj_b, 16384, 384, 384);
}

// Round 5
// 191.062 us; speedup vs baseline: 2.2584x; 1.0126x over previous
//
#include <hip/hip_runtime.h>
#include <stdint.h>
#include <math.h>

#define BB 8
#define SEQ 2048
#define CDIM 384
#define NH 6
#define HD 64
#define QKVN 1152

typedef __attribute__((ext_vector_type(8))) __bf16 bf16x8;
typedef __attribute__((ext_vector_type(4))) float f32x4;
typedef __attribute__((ext_vector_type(4))) unsigned short ushort4v;

__device__ __forceinline__ unsigned short f2bf(float f) {
  unsigned int u = __float_as_uint(f);
  u += 0x7fffu + ((u >> 16) & 1u);
  return (unsigned short)(u >> 16);
}

// fp32 -> bf16 conversion, 4 elems/thread
__global__ void k_convert(const float* __restrict__ src, unsigned short* __restrict__ dst, int n4) {
  int i = blockIdx.x * blockDim.x + threadIdx.x;
  if (i >= n4) return;
  float4 f = reinterpret_cast<const float4*>(src)[i];
  ushort4v u;
  u.x = f2bf(f.x); u.y = f2bf(f.y); u.z = f2bf(f.z); u.w = f2bf(f.w);
  reinterpret_cast<ushort4v*>(dst)[i] = u;
}

__device__ __forceinline__ void gload_lds16(const unsigned short* g, unsigned short* l) {
  __builtin_amdgcn_global_load_lds((const __attribute__((address_space(1))) void*)g,
                                   (__attribute__((address_space(3))) void*)l, 16, 0, 0);
}

// C[M,Nc] = A[M,K] * Bm[Nc,K]^T   (both row-major bf16, K contiguous; m97 structure)
template<int OUT_F32>
__global__ __launch_bounds__(256, 2) void k_gemm_bt(
    const unsigned short* __restrict__ A, const unsigned short* __restrict__ Bm,
    unsigned short* __restrict__ Cb, float* __restrict__ Cf,
    const float* __restrict__ bias, int M, int Nc, int K)
{
  __shared__ unsigned short lA[128 * 32];
  __shared__ unsigned short lB[128 * 32];
  const int t = threadIdx.x;
  const int w = t >> 6, l = t & 63;
  const int wr = w >> 1, wc = w & 1;
  const int row0 = blockIdx.x * 128, col0 = blockIdx.y * 128;
  const f32x4 vzero = {0.f, 0.f, 0.f, 0.f};
  f32x4 acc[4][4];
#pragma unroll
  for (int m = 0; m < 4; ++m)
#pragma unroll
    for (int n = 0; n < 4; ++n) acc[m][n] = vzero;

  const int srow = w * 16 + (l >> 2);
  const int scol = (l & 3) * 8;
  const int lr = l & 15, kc = (l >> 4) * 8;

  for (int k0 = 0; k0 < K; k0 += 32) {
#pragma unroll
    for (int r = 0; r < 2; ++r) {
      gload_lds16(A + (size_t)(row0 + r * 64 + srow) * K + k0 + scol,
                  &lA[(r * 64 + srow) * 32 + scol]);
      gload_lds16(Bm + (size_t)(col0 + r * 64 + srow) * K + k0 + scol,
                  &lB[(r * 64 + srow) * 32 + scol]);
    }
    __syncthreads();
    bf16x8 af[4], bfr[4];
#pragma unroll
    for (int m = 0; m < 4; ++m)
      af[m] = *(const bf16x8*)&lA[(wr * 64 + m * 16 + lr) * 32 + kc];
#pragma unroll
    for (int n = 0; n < 4; ++n)
      bfr[n] = *(const bf16x8*)&lB[(wc * 64 + n * 16 + lr) * 32 + kc];
#pragma unroll
    for (int m = 0; m < 4; ++m)
#pragma unroll
      for (int n = 0; n < 4; ++n)
        acc[m][n] = __builtin_amdgcn_mfma_f32_16x16x32_bf16(af[m], bfr[n], acc[m][n], 0, 0, 0);
    __syncthreads();
  }

#pragma unroll
  for (int m = 0; m < 4; ++m) {
    const int row = row0 + wr * 64 + m * 16 + (l >> 4) * 4;
#pragma unroll
    for (int n = 0; n < 4; ++n) {
      const int col = col0 + wc * 64 + n * 16 + (l & 15);
      if (OUT_F32) {
        const float bv = bias[col];
#pragma unroll
        for (int j = 0; j < 4; ++j)
          Cf[(size_t)(row + j) * Nc + col] = acc[m][n][j] + bv;
      } else {
#pragma unroll
        for (int j = 0; j < 4; ++j)
          Cb[(size_t)(row + j) * Nc + col] = f2bf(acc[m][n][j]);
      }
    }
  }
}

// V slice of qkv (b,n,768 + h*64 + d) -> VT[(b*H+h), d, n]  (bf16)
__global__ void k_vtrans(const unsigned short* __restrict__ qkv, unsigned short* __restrict__ vt)
{
  __shared__ unsigned short tile[64][76];
  const int bh = blockIdx.x;
  const int b = bh / NH, h = bh - b * NH;
  const int n0 = blockIdx.y * 64;
  const int t = threadIdx.x;
  const int rr0 = t >> 4;
  const int c4 = (t & 15) * 4;
  const unsigned short* src = qkv + (size_t)(b * SEQ + n0) * QKVN + 2 * CDIM + h * HD;
#pragma unroll
  for (int rr = 0; rr < 4; ++rr) {
    int n = rr * 16 + rr0;
    ushort4v v = *(const ushort4v*)(src + (size_t)n * QKVN + c4);
    *(ushort4v*)&tile[n][c4] = v;
  }
  __syncthreads();
  unsigned short* dst = vt + (size_t)bh * HD * SEQ + n0;
#pragma unroll
  for (int rr = 0; rr < 4; ++rr) {
    int d = rr * 16 + rr0;
    ushort4v v;
    v.x = tile[c4 + 0][d];
    v.y = tile[c4 + 1][d];
    v.z = tile[c4 + 2][d];
    v.w = tile[c4 + 3][d];
    *(ushort4v*)(dst + (size_t)d * SEQ + c4) = v;
  }
}

// Flash attention v5: swapped QK^T (S^T: q = lane&15, keys in regs) -> per-lane
// softmax, float4 mask loads, packed-u32 P redistribution via swizzled LDS.
// 1536 blocks x 4 waves, KT=64 double-buffered K/V LDS, log2 domain, defer-rescale.
__global__ __launch_bounds__(256, 4) void k_attn(
    const unsigned short* __restrict__ qkv, const float* __restrict__ mask,
    const unsigned short* __restrict__ vt, unsigned short* __restrict__ aout)
{
  const int bid = blockIdx.x;
  const int b = bid & 7;            // batch -> XCD
  const int g2 = bid >> 3;          // 0..191
  const int h = g2 % NH;
  const int nt = g2 / NH;           // 0..31
  const int t = threadIdx.x;
  const int w = t >> 6, l = t & 63;
  const int gk = l >> 4, c = l & 15;
  const int q0 = nt * 64 + w * 16;  // wave handles q0..q0+15

  __shared__ unsigned short lK[2][4096];
  __shared__ unsigned short lV[2][4096];
  __shared__ unsigned int lP[4][512];  // per-wave 16 rows x 32 u32, XOR-swizzled
  unsigned int* prow = lP[w] + c * 32;

  const unsigned short* qb = qkv + (size_t)(b * SEQ + q0) * QKVN + h * HD;
  const unsigned short* kb = qkv + (size_t)(b * SEQ) * QKVN + CDIM + h * HD;
  const unsigned short* vb = vt + (size_t)(b * NH + h) * HD * SEQ;
  const float* mrowc = mask + ((size_t)b * SEQ + q0 + c) * SEQ;  // this lane's q-row

  // staging: 256 threads x 16B x 2 issues = 64x64 bf16 tile
  const int trow = t >> 3, tg = t & 7;
  const int glog = tg ^ (trow & 7);
  const size_t kSrc = (size_t)trow * QKVN + glog * 8;
  const size_t vSrc = (size_t)trow * SEQ + glog * 8;

  // fragment ds_read offsets (elems): row 16j+c (K) / dt*16+c (V), granule XOR row&7
  const int fr0 = c * 64 + ((gk) ^ (c & 7)) * 8;
  const int fr1 = c * 64 + ((4 + gk) ^ (c & 7)) * 8;
  const int cx = (c & 7) << 2;       // P-slot XOR swizzle

  // Q as B'-frag (col=q=c, d-chunk gk*8), pre-scaled by rsqrt(D)*log2(e)
  bf16x8 qf0 = *(const bf16x8*)(qb + (size_t)c * QKVN + gk * 8);
  bf16x8 qf1 = *(const bf16x8*)(qb + (size_t)c * QKVN + 32 + gk * 8);
#pragma unroll
  for (int i = 0; i < 8; ++i) {
    qf0[i] = (__bf16)((float)qf0[i] * 0.18033688f);
    qf1[i] = (__bf16)((float)qf1[i] * 0.18033688f);
  }

  const f32x4 vzero = {0.f, 0.f, 0.f, 0.f};
  f32x4 acco[4];
  float mreg = -INFINITY, asum = 0.f;
#pragma unroll
  for (int dt = 0; dt < 4; ++dt) acco[dt] = vzero;

  // prologue: stage kt=0 into buf 0; load first mask tile (float4 per j)
#pragma unroll
  for (int j = 0; j < 2; ++j) {
    gload_lds16(kb + (size_t)j * 32 * QKVN + kSrc, &lK[0][j * 2048 + t * 8]);
    gload_lds16(vb + (size_t)j * 32 * SEQ + vSrc, &lV[0][j * 2048 + t * 8]);
  }
  float4 mk[4];
#pragma unroll
  for (int j = 0; j < 4; ++j)
    mk[j] = *(const float4*)(mrowc + 16 * j + 4 * gk);
  int buf = 0;

  for (int kt = 0; kt < SEQ; kt += 64) {
    const bool haveNext = (kt + 64 < SEQ);
    __syncthreads();
    if (haveNext) {
#pragma unroll
      for (int j = 0; j < 2; ++j) {
        gload_lds16(kb + (size_t)(kt + 64 + j * 32) * QKVN + kSrc, &lK[buf ^ 1][j * 2048 + t * 8]);
        gload_lds16(vb + (kt + 64) + (size_t)j * 32 * SEQ + vSrc, &lV[buf ^ 1][j * 2048 + t * 8]);
      }
    }

    // swapped QK^T: S^T[key=16j+4gk+r][q=c] (log2 domain via pre-scaled Q)
    f32x4 s[4];
#pragma unroll
    for (int j = 0; j < 4; ++j) {
      bf16x8 kfa = *(const bf16x8*)&lK[buf][j * 1024 + fr0];
      bf16x8 kfb = *(const bf16x8*)&lK[buf][j * 1024 + fr1];
      s[j] = __builtin_amdgcn_mfma_f32_16x16x32_bf16(kfa, qf0, vzero, 0, 0, 0);
      s[j] = __builtin_amdgcn_mfma_f32_16x16x32_bf16(kfb, qf1, s[j], 0, 0, 0);
    }

    // masked log2-scores in place; component r <-> key 4gk+r <-> float4 lane r
#pragma unroll
    for (int j = 0; j < 4; ++j) {
      const float* mkf = (const float*)&mk[j];
#pragma unroll
      for (int r = 0; r < 4; ++r)
        s[j][r] = fmaf(mkf[r], -144269.50f, s[j][r]);
    }

    // reload mask for next tile (single buffer: WAR after last use; latency
    // hidden under softmax+PV+barrier)
    if (haveNext) {
#pragma unroll
      for (int j = 0; j < 4; ++j)
        mk[j] = *(const float4*)(mrowc + kt + 64 + 16 * j + 4 * gk);
    }

    // per-lane max over own 16 keys, then across the 4 gk-groups
    float tm = fmaxf(fmaxf(fmaxf(s[0][0], s[0][1]), fmaxf(s[0][2], s[0][3])),
                     fmaxf(fmaxf(s[1][0], s[1][1]), fmaxf(s[1][2], s[1][3])));
    tm = fmaxf(tm, fmaxf(fmaxf(fmaxf(s[2][0], s[2][1]), fmaxf(s[2][2], s[2][3])),
                         fmaxf(fmaxf(s[3][0], s[3][1]), fmaxf(s[3][2], s[3][3]))));
    tm = fmaxf(tm, __shfl_xor(tm, 16));
    tm = fmaxf(tm, __shfl_xor(tm, 32));

    // defer-rescale (T13, thr=8 in log2 domain)
    if (__any(tm > mreg + 8.f)) {
      const float mn = fmaxf(mreg, tm);
      const float al = __builtin_amdgcn_exp2f(mreg - mn);
      mreg = mn;
      asum *= al;
      // acco rows are q=4gk+r: fetch al for those q's (holder lane c'=4gk+r)
      float alr[4];
#pragma unroll
      for (int r = 0; r < 4; ++r)
        alr[r] = __shfl(al, 20 * gk + r);
#pragma unroll
      for (int dt = 0; dt < 4; ++dt)
#pragma unroll
        for (int r = 0; r < 4; ++r)
          acco[dt][r] *= alr[r];
    }

    // P = exp2(s - m) in place, then row-sum (own 16 + cross-group)
#pragma unroll
    for (int j = 0; j < 4; ++j)
#pragma unroll
      for (int r = 0; r < 4; ++r)
        s[j][r] = __builtin_amdgcn_exp2f(s[j][r] - mreg);
    float rs = ((s[0][0] + s[0][1]) + (s[0][2] + s[0][3]))
             + ((s[1][0] + s[1][1]) + (s[1][2] + s[1][3]))
             + ((s[2][0] + s[2][1]) + (s[2][2] + s[2][3]))
             + ((s[3][0] + s[3][1]) + (s[3][2] + s[3][3]));
    rs += __shfl_xor(rs, 16);
    rs += __shfl_xor(rs, 32);
    asum += rs;

    // pack P pairs to bf16x2 u32s; redistribute keys via swizzled LDS:
    // logical slot = keypair index (key>>1); physical = slot ^ ((c&7)<<2)
    unsigned int pk[8];
#pragma unroll
    for (int j = 0; j < 4; ++j) {
      asm("v_cvt_pk_bf16_f32 %0, %1, %2" : "=v"(pk[2 * j]) : "v"(s[j][0]), "v"(s[j][1]));
      asm("v_cvt_pk_bf16_f32 %0, %1, %2" : "=v"(pk[2 * j + 1]) : "v"(s[j][2]), "v"(s[j][3]));
    }
    __asm__ volatile("" ::: "memory");
#pragma unroll
    for (int j = 0; j < 4; ++j) {
      prow[(8 * j + 2 * gk + 0) ^ cx] = pk[2 * j];
      prow[(8 * j + 2 * gk + 1) ^ cx] = pk[2 * j + 1];
    }
    __asm__ volatile("" ::: "memory");
    // A'-frag: row=q=c, keys gk*8..+7 (pf0) / 32+gk*8..+7 (pf1)
    bf16x8 pf0 = *(const bf16x8*)(prow + ((4 * gk) ^ cx));
    bf16x8 pf1 = *(const bf16x8*)(prow + ((16 + 4 * gk) ^ cx));
    __asm__ volatile("" ::: "memory");

    // PV: O[q=4gk+r][d=dt*16+c]
#pragma unroll
    for (int dt = 0; dt < 4; ++dt) {
      bf16x8 vf0 = *(const bf16x8*)&lV[buf][dt * 1024 + fr0];
      bf16x8 vf1 = *(const bf16x8*)&lV[buf][dt * 1024 + fr1];
      acco[dt] = __builtin_amdgcn_mfma_f32_16x16x32_bf16(pf0, vf0, acco[dt], 0, 0, 0);
      acco[dt] = __builtin_amdgcn_mfma_f32_16x16x32_bf16(pf1, vf1, acco[dt], 0, 0, 0);
    }
    buf ^= 1;
  }

  // normalize: asum lives at holder lane c'=4gk+r; out rows q0+4gk+r
  float invr[4];
#pragma unroll
  for (int r = 0; r < 4; ++r)
    invr[r] = 1.0f / __shfl(asum, 20 * gk + r);
  unsigned short* ob = aout + (size_t)(b * SEQ + q0) * CDIM + h * HD;
#pragma unroll
  for (int r = 0; r < 4; ++r)
#pragma unroll
    for (int dt = 0; dt < 4; ++dt)
      ob[(size_t)(4 * gk + r) * CDIM + dt * 16 + c] = f2bf(acco[dt][r] * invr[r]);
}

extern "C" void kernel_launch(void* const* d_in, const int* in_sizes, int n_in,
                              void* d_out, int out_size, void* d_ws, size_t ws_size,
                              hipStream_t stream) {
  (void)in_sizes; (void)n_in; (void)out_size; (void)ws_size;
  const float* x      = (const float*)d_in[0];
  const float* mask   = (const float*)d_in[2];
  const float* qkv_w  = (const float*)d_in[3];
  const float* proj_w = (const float*)d_in[4];
  const float* proj_b = (const float*)d_in[5];
  float* out = (float*)d_out;
  char* ws = (char*)d_ws;

  unsigned short* xb    = (unsigned short*)(ws + 0);         // x bf16:      12,582,912
  unsigned short* wqb   = (unsigned short*)(ws + 12582912);  // qkv_w bf16:     884,736
  unsigned short* wpb   = (unsigned short*)(ws + 13467648);  // proj_w bf16:    294,912
  unsigned short* qkvb  = (unsigned short*)(ws + 13762560);  // qkv bf16:    37,748,736
  unsigned short* vtb   = (unsigned short*)(ws + 51511296);  // V^T bf16:    12,582,912
  unsigned short* aoutb = (unsigned short*)(ws + 64094208);  // attn out:    12,582,912

  k_convert<<<6144, 256, 0, stream>>>(x, xb, 1572864);
  k_convert<<<432, 256, 0, stream>>>(qkv_w, wqb, 110592);
  k_convert<<<144, 256, 0, stream>>>(proj_w, wpb, 36864);
  k_gemm_bt<0><<<dim3(128, 9), 256, 0, stream>>>(xb, wqb, qkvb, nullptr, nullptr, 16384, 1152, 384);
  k_vtrans<<<dim3(48, 32), 256, 0, stream>>>(qkvb, vtb);
  k_attn<<<1536, 256, 0, stream>>>(qkvb, mask, vtb, aoutb);
  k_gemm_bt<1><<<dim3(128, 3), 256, 0, stream>>>(aoutb, wpb, nullptr, out, proj_b, 16384, 384, 384);
}